// Round 1
// baseline (2100.273 us; speedup 1.0000x reference)
//
#include <hip/hip_runtime.h>
#include <math.h>

#define Bn 8
#define Vn 5000
#define Cn 256
#define Kn 200

// workspace layout (floats):
//   AB  [16][200][256] @ 0        (mats 0..7 = A per batch, 8..15 = Bc per batch)
//   AAT [16][200][200] @ 819200   (mats 0..7 = A·Aᵀ,      8..15 = B·Aᵀ)
#define AB_OFF  0
#define AAT_OFF 819200

// ---------------------------------------------------------------------------
// K1: A[b] = evecs_trans_x[b] (200x5000) @ feat_x[b] (5000x256), same for y.
// 16 GEMMs, split-K=8, atomicAdd accumulate. 64x64 tile, BK=32, 4x4 micro.
// ---------------------------------------------------------------------------
__global__ __launch_bounds__(256) void k_gemm_ab(
    const float* __restrict__ fx, const float* __restrict__ fy,
    const float* __restrict__ etx, const float* __restrict__ ety,
    float* __restrict__ AB)
{
    __shared__ float Es[64 * 33];
    __shared__ float Fs[32 * 64];
    const int bid  = blockIdx.x;
    const int ks   = bid & 7;
    const int t    = bid >> 3;
    const int mat  = t >> 4;
    const int tile = t & 15;
    const int tr = tile >> 2, tc = tile & 3;
    const int b = mat & 7, which = mat >> 3;
    const float* __restrict__ E = (which ? ety : etx) + b * Kn * Vn;
    const float* __restrict__ F = (which ? fy : fx) + b * Vn * Cn;
    float* __restrict__ out = AB + mat * Kn * Cn;
    const int row0 = tr * 64, col0 = tc * 64;
    const int kstart = ks * 640;
    const int kend = (kstart + 640 < Vn) ? (kstart + 640) : Vn;
    const int tid = threadIdx.x;
    const int tx = tid & 15, ty = tid >> 4;
    float acc[4][4] = {};

    for (int k0 = kstart; k0 < kend; k0 += 32) {
#pragma unroll
        for (int i = 0; i < 8; ++i) {
            int idx = tid + i * 256;
            int r = idx >> 5, kk = idx & 31;
            int gr = row0 + r, gk = k0 + kk;
            Es[r * 33 + kk] = (gr < Kn && gk < kend) ? E[gr * Vn + gk] : 0.f;
        }
#pragma unroll
        for (int i = 0; i < 8; ++i) {
            int idx = tid + i * 256;
            int v = idx >> 6, cc = idx & 63;
            int gv = k0 + v;
            Fs[v * 64 + cc] = (gv < kend) ? F[gv * Cn + col0 + cc] : 0.f;
        }
        __syncthreads();
#pragma unroll
        for (int kk = 0; kk < 32; ++kk) {
            float a0 = Es[(ty * 4 + 0) * 33 + kk];
            float a1 = Es[(ty * 4 + 1) * 33 + kk];
            float a2 = Es[(ty * 4 + 2) * 33 + kk];
            float a3 = Es[(ty * 4 + 3) * 33 + kk];
            float4 bv = *(const float4*)&Fs[kk * 64 + tx * 4];
            acc[0][0] += a0 * bv.x; acc[0][1] += a0 * bv.y; acc[0][2] += a0 * bv.z; acc[0][3] += a0 * bv.w;
            acc[1][0] += a1 * bv.x; acc[1][1] += a1 * bv.y; acc[1][2] += a1 * bv.z; acc[1][3] += a1 * bv.w;
            acc[2][0] += a2 * bv.x; acc[2][1] += a2 * bv.y; acc[2][2] += a2 * bv.z; acc[2][3] += a2 * bv.w;
            acc[3][0] += a3 * bv.x; acc[3][1] += a3 * bv.y; acc[3][2] += a3 * bv.z; acc[3][3] += a3 * bv.w;
        }
        __syncthreads();
    }
#pragma unroll
    for (int m = 0; m < 4; ++m) {
        int gr = row0 + ty * 4 + m;
        if (gr < Kn) {
#pragma unroll
            for (int n = 0; n < 4; ++n)
                atomicAdd(&out[gr * Cn + col0 + tx * 4 + n], acc[m][n]);
        }
    }
}

// ---------------------------------------------------------------------------
// K2: AAT[m] = X[m] (200x256) @ A2ᵀ (256x200), X = A (m<8) or Bc (m>=8),
// A2 = A[b].  NT layout, contraction over contiguous c.
// ---------------------------------------------------------------------------
__global__ __launch_bounds__(256) void k_gemm_nt(
    const float* __restrict__ AB, float* __restrict__ AAT)
{
    __shared__ float Xs[64 * 33];
    __shared__ float As[64 * 33];
    const int bid = blockIdx.x;
    const int mat = bid >> 4;
    const int tile = bid & 15;
    const int tr = tile >> 2, tc = tile & 3;
    const float* __restrict__ X  = AB + mat * Kn * Cn;
    const float* __restrict__ A2 = AB + (mat & 7) * Kn * Cn;
    float* __restrict__ out = AAT + mat * Kn * Kn;
    const int r0 = tr * 64, j0 = tc * 64;
    const int tid = threadIdx.x;
    const int tx = tid & 15, ty = tid >> 4;
    float acc[4][4] = {};

    for (int c0 = 0; c0 < Cn; c0 += 32) {
#pragma unroll
        for (int i = 0; i < 8; ++i) {
            int idx = tid + i * 256;
            int r = idx >> 5, kk = idx & 31;
            int gr = r0 + r;
            Xs[r * 33 + kk] = (gr < Kn) ? X[gr * Cn + c0 + kk] : 0.f;
            int gj = j0 + r;
            As[r * 33 + kk] = (gj < Kn) ? A2[gj * Cn + c0 + kk] : 0.f;
        }
        __syncthreads();
#pragma unroll
        for (int kk = 0; kk < 32; ++kk) {
            float a0 = Xs[(ty * 4 + 0) * 33 + kk];
            float a1 = Xs[(ty * 4 + 1) * 33 + kk];
            float a2 = Xs[(ty * 4 + 2) * 33 + kk];
            float a3 = Xs[(ty * 4 + 3) * 33 + kk];
            float b0 = As[(tx * 4 + 0) * 33 + kk];
            float b1 = As[(tx * 4 + 1) * 33 + kk];
            float b2 = As[(tx * 4 + 2) * 33 + kk];
            float b3 = As[(tx * 4 + 3) * 33 + kk];
            acc[0][0] += a0 * b0; acc[0][1] += a0 * b1; acc[0][2] += a0 * b2; acc[0][3] += a0 * b3;
            acc[1][0] += a1 * b0; acc[1][1] += a1 * b1; acc[1][2] += a1 * b2; acc[1][3] += a1 * b3;
            acc[2][0] += a2 * b0; acc[2][1] += a2 * b1; acc[2][2] += a2 * b2; acc[2][3] += a2 * b3;
            acc[3][0] += a3 * b0; acc[3][1] += a3 * b1; acc[3][2] += a3 * b2; acc[3][3] += a3 * b3;
        }
        __syncthreads();
    }
#pragma unroll
    for (int m = 0; m < 4; ++m) {
        int gr = r0 + ty * 4 + m;
        if (gr < Kn) {
#pragma unroll
            for (int n = 0; n < 4; ++n) {
                int gj = j0 + tx * 4 + n;
                if (gj < Kn) out[gr * Kn + gj] = acc[m][n];
            }
        }
    }
}

// ---------------------------------------------------------------------------
// K3: per (b,i): solve (AAt[b] + lambda*diag(D[b,i,:])) x = BAt[b,i,:].
// Whole 200x201 augmented matrix in LDS (160,800 B). Blocked no-pivot LU,
// NB=8, one barrier per mini-step (factors never overwritten; recomputed as
// raw*invpivot), rank-8 trailing update with pivot rows cached in VGPRs,
// wave-synchronous back-substitution on wave 0.
// ---------------------------------------------------------------------------
__global__ __launch_bounds__(512) void k_solve(
    const float* __restrict__ AAT,
    const float* __restrict__ evalx, const float* __restrict__ evaly,
    const float* __restrict__ graw, const float* __restrict__ lraw,
    float* __restrict__ out)
{
    __shared__ float sM[Kn * 201];
    __shared__ float sAux[16];
    const int bid = blockIdx.x;
    const int b = bid / 200;
    const int i = bid - b * 200;
    const int tid = threadIdx.x;
    const float* __restrict__ Sb = AAT + b * 40000;
    const float* __restrict__ Rb = AAT + 320000 + bid * 200;
    const float* __restrict__ ex = evalx + b * Kn;
    const float* __restrict__ ey = evaly + b * Kn;

    // load S (stride 201) and rhs (column 200)
    for (int e = tid; e < 40000; e += 512) {
        int r = e / 200;
        int c = e - r * 200;
        sM[r * 201 + c] = Sb[e];
    }
    if (tid < 200) sM[tid * 201 + 200] = Rb[tid];

    // scaling = max(max ex, max ey) over the batch (wave 0)
    if (tid < 64) {
        float mx = 0.f;
        for (int j = tid; j < 200; j += 64) mx = fmaxf(mx, fmaxf(ex[j], ey[j]));
#pragma unroll
        for (int s = 32; s > 0; s >>= 1) mx = fmaxf(mx, __shfl_down(mx, s));
        if (tid == 0) sAux[0] = mx;
    }
    __syncthreads();

    // diagonal: += lambda * D[b,i,r]
    if (tid < 200) {
        int r = tid;
        float s = sAux[0];
        float g = 1.f / (1.f + expf(-graw[0]));
        float lr = lraw[0];
        float sp = fmaxf(lr, 0.f) + log1pf(expf(-fabsf(lr)));   // stable softplus
        float lmb = 10.f + sp * (990.f / 1000.f);
        lmb = fminf(fmaxf(lmb, 10.f), 1000.f);
        float gx = powf(ex[i] / s, g);
        float gy = powf(ey[r] / s, g);
        float d1 = 1.f / (gx * gx + 1.f);
        float d2 = 1.f / (gy * gy + 1.f);
        float re = gy * d2 - gx * d1;
        float im = d2 - d1;
        sM[r * 201 + r] += lmb * (re * re + im * im);
    }

    // blocked LU, NB = 8
    for (int k = 0; k < 200; k += 8) {
        // mini-steps c = 0..6 (c = 7 needs no panel/U-row work)
        for (int c = 0; c < 7; ++c) {
            int kc = k + c;
            __syncthreads();
            float invp = 1.f / sM[kc * 201 + kc];
            if (tid == 0) sAux[8 + c] = invp;
            int nr1 = 199 - kc;                    // rows kc+1..199
            if (tid < nr1) {
                int r = kc + 1 + tid;
                float f = sM[r * 201 + kc] * invp;
                for (int j = kc + 1; j < k + 8; ++j)
                    sM[r * 201 + j] -= f * sM[kc * 201 + j];
            } else if (tid >= 256) {
                // U-rows: rows kc+1..k+7, trailing cols k+8..200
                for (int rr = kc + 1; rr <= k + 7; ++rr) {
                    float f2 = sM[rr * 201 + kc] * invp;
                    for (int j = k + 8 + (tid - 256); j <= 200; j += 256)
                        sM[rr * 201 + j] -= f2 * sM[kc * 201 + j];
                }
            }
        }
        __syncthreads();
        // rank-8 trailing update: rows k+8..199, cols k+8..200
        float invs[8];
#pragma unroll
        for (int c = 0; c < 7; ++c) invs[c] = sAux[8 + c];
        invs[7] = 1.f / sM[(k + 7) * 201 + (k + 7)];
        const int w = tid >> 6, l = tid & 63;
        const int jb0 = k + 8;
        float pv[4][8];
#pragma unroll
        for (int ch = 0; ch < 4; ++ch) {
            int j = jb0 + ch * 64 + l;
            if (j <= 200) {
#pragma unroll
                for (int c = 0; c < 8; ++c) pv[ch][c] = sM[(k + c) * 201 + j];
            }
        }
        for (int r = k + 8 + w; r < 200; r += 8) {
            float f[8];
#pragma unroll
            for (int c = 0; c < 8; ++c) f[c] = sM[r * 201 + k + c] * invs[c];
#pragma unroll
            for (int ch = 0; ch < 4; ++ch) {
                int j = jb0 + ch * 64 + l;
                if (j <= 200) {
                    float a = sM[r * 201 + j];
#pragma unroll
                    for (int c = 0; c < 8; ++c) a -= f[c] * pv[ch][c];
                    sM[r * 201 + j] = a;
                }
            }
        }
    }
    __syncthreads();

    // back substitution, wave 0, wave-synchronous (no barriers)
    if (tid < 64) {
        for (int k = 199; k >= 0; --k) {
            float xk = sM[k * 201 + 200] / sM[k * 201 + k];
            if (tid == 0) sM[k * 201 + 200] = xk;
#pragma unroll
            for (int u = 0; u < 4; ++u) {
                int r = tid + (u << 6);
                if (r < k) sM[r * 201 + 200] -= sM[r * 201 + k] * xk;
            }
        }
    }
    __syncthreads();

    if (tid < 200) out[bid * 200 + tid] = sM[tid * 201 + 200];
}

// ---------------------------------------------------------------------------
extern "C" void kernel_launch(void* const* d_in, const int* in_sizes, int n_in,
                              void* d_out, int out_size, void* d_ws, size_t ws_size,
                              hipStream_t stream)
{
    const float* fx   = (const float*)d_in[0];   // feat_x   [8,5000,256]
    const float* fy   = (const float*)d_in[1];   // feat_y
    const float* evx  = (const float*)d_in[2];   // evals_x  [8,200]
    const float* evy  = (const float*)d_in[3];   // evals_y
    const float* etx  = (const float*)d_in[4];   // evecs_trans_x [8,200,5000]
    const float* ety  = (const float*)d_in[5];   // evecs_trans_y
    const float* graw = (const float*)d_in[6];   // gamma_raw scalar
    const float* lraw = (const float*)d_in[7];   // lambda_raw scalar
    float* out = (float*)d_out;
    float* ws  = (float*)d_ws;

    // zero the split-K accumulation region (AB)
    hipMemsetAsync(ws + AB_OFF, 0, (size_t)16 * Kn * Cn * sizeof(float), stream);

    k_gemm_ab<<<dim3(2048), dim3(256), 0, stream>>>(fx, fy, etx, ety, ws + AB_OFF);
    k_gemm_nt<<<dim3(256), dim3(256), 0, stream>>>(ws + AB_OFF, ws + AAT_OFF);
    k_solve<<<dim3(1600), dim3(512), 0, stream>>>(ws + AAT_OFF, evx, evy, graw, lraw, out);
}

// Round 3
// 1521.080 us; speedup vs baseline: 1.3808x; 1.3808x over previous
//
#include <hip/hip_runtime.h>
#include <math.h>

#define Bn 8
#define Vn 5000
#define Cn 256
#define Kn 200

// workspace layout (floats):
//   AB  [16][200][256] @ 0        (mats 0..7 = A per batch, 8..15 = Bc per batch)
//   AAT [16][200][200] @ 819200   (mats 0..7 = A·Aᵀ,      8..15 = B·Aᵀ)
#define AB_OFF  0
#define AAT_OFF 819200

// ---------------------------------------------------------------------------
// K1: A[b] = evecs_trans_x[b] (200x5000) @ feat_x[b] (5000x256), same for y.
// 16 GEMMs, split-K=8, atomicAdd accumulate. 64x64 tile, BK=32, 4x4 micro.
// ---------------------------------------------------------------------------
__global__ __launch_bounds__(256) void k_gemm_ab(
    const float* __restrict__ fx, const float* __restrict__ fy,
    const float* __restrict__ etx, const float* __restrict__ ety,
    float* __restrict__ AB)
{
    __shared__ float Es[64 * 33];
    __shared__ float Fs[32 * 64];
    const int bid  = blockIdx.x;
    const int ks   = bid & 7;
    const int t    = bid >> 3;
    const int mat  = t >> 4;
    const int tile = t & 15;
    const int tr = tile >> 2, tc = tile & 3;
    const int b = mat & 7, which = mat >> 3;
    const float* __restrict__ E = (which ? ety : etx) + b * Kn * Vn;
    const float* __restrict__ F = (which ? fy : fx) + b * Vn * Cn;
    float* __restrict__ out = AB + mat * Kn * Cn;
    const int row0 = tr * 64, col0 = tc * 64;
    const int kstart = ks * 640;
    const int kend = (kstart + 640 < Vn) ? (kstart + 640) : Vn;
    const int tid = threadIdx.x;
    const int tx = tid & 15, ty = tid >> 4;
    float acc[4][4] = {};

    for (int k0 = kstart; k0 < kend; k0 += 32) {
#pragma unroll
        for (int i = 0; i < 8; ++i) {
            int idx = tid + i * 256;
            int r = idx >> 5, kk = idx & 31;
            int gr = row0 + r, gk = k0 + kk;
            Es[r * 33 + kk] = (gr < Kn && gk < kend) ? E[gr * Vn + gk] : 0.f;
        }
#pragma unroll
        for (int i = 0; i < 8; ++i) {
            int idx = tid + i * 256;
            int v = idx >> 6, cc = idx & 63;
            int gv = k0 + v;
            Fs[v * 64 + cc] = (gv < kend) ? F[gv * Cn + col0 + cc] : 0.f;
        }
        __syncthreads();
#pragma unroll
        for (int kk = 0; kk < 32; ++kk) {
            float a0 = Es[(ty * 4 + 0) * 33 + kk];
            float a1 = Es[(ty * 4 + 1) * 33 + kk];
            float a2 = Es[(ty * 4 + 2) * 33 + kk];
            float a3 = Es[(ty * 4 + 3) * 33 + kk];
            float4 bv = *(const float4*)&Fs[kk * 64 + tx * 4];
            acc[0][0] += a0 * bv.x; acc[0][1] += a0 * bv.y; acc[0][2] += a0 * bv.z; acc[0][3] += a0 * bv.w;
            acc[1][0] += a1 * bv.x; acc[1][1] += a1 * bv.y; acc[1][2] += a1 * bv.z; acc[1][3] += a1 * bv.w;
            acc[2][0] += a2 * bv.x; acc[2][1] += a2 * bv.y; acc[2][2] += a2 * bv.z; acc[2][3] += a2 * bv.w;
            acc[3][0] += a3 * bv.x; acc[3][1] += a3 * bv.y; acc[3][2] += a3 * bv.z; acc[3][3] += a3 * bv.w;
        }
        __syncthreads();
    }
#pragma unroll
    for (int m = 0; m < 4; ++m) {
        int gr = row0 + ty * 4 + m;
        if (gr < Kn) {
#pragma unroll
            for (int n = 0; n < 4; ++n)
                atomicAdd(&out[gr * Cn + col0 + tx * 4 + n], acc[m][n]);
        }
    }
}

// ---------------------------------------------------------------------------
// K2: AAT[m] = X[m] (200x256) @ A2ᵀ (256x200), X = A (m<8) or Bc (m>=8),
// A2 = A[b].  NT layout, contraction over contiguous c.
// ---------------------------------------------------------------------------
__global__ __launch_bounds__(256) void k_gemm_nt(
    const float* __restrict__ AB, float* __restrict__ AAT)
{
    __shared__ float Xs[64 * 33];
    __shared__ float As[64 * 33];
    const int bid = blockIdx.x;
    const int mat = bid >> 4;
    const int tile = bid & 15;
    const int tr = tile >> 2, tc = tile & 3;
    const float* __restrict__ X  = AB + mat * Kn * Cn;
    const float* __restrict__ A2 = AB + (mat & 7) * Kn * Cn;
    float* __restrict__ out = AAT + mat * Kn * Kn;
    const int r0 = tr * 64, j0 = tc * 64;
    const int tid = threadIdx.x;
    const int tx = tid & 15, ty = tid >> 4;
    float acc[4][4] = {};

    for (int c0 = 0; c0 < Cn; c0 += 32) {
#pragma unroll
        for (int i = 0; i < 8; ++i) {
            int idx = tid + i * 256;
            int r = idx >> 5, kk = idx & 31;
            int gr = r0 + r;
            Xs[r * 33 + kk] = (gr < Kn) ? X[gr * Cn + c0 + kk] : 0.f;
            int gj = j0 + r;
            As[r * 33 + kk] = (gj < Kn) ? A2[gj * Cn + c0 + kk] : 0.f;
        }
        __syncthreads();
#pragma unroll
        for (int kk = 0; kk < 32; ++kk) {
            float a0 = Xs[(ty * 4 + 0) * 33 + kk];
            float a1 = Xs[(ty * 4 + 1) * 33 + kk];
            float a2 = Xs[(ty * 4 + 2) * 33 + kk];
            float a3 = Xs[(ty * 4 + 3) * 33 + kk];
            float b0 = As[(tx * 4 + 0) * 33 + kk];
            float b1 = As[(tx * 4 + 1) * 33 + kk];
            float b2 = As[(tx * 4 + 2) * 33 + kk];
            float b3 = As[(tx * 4 + 3) * 33 + kk];
            acc[0][0] += a0 * b0; acc[0][1] += a0 * b1; acc[0][2] += a0 * b2; acc[0][3] += a0 * b3;
            acc[1][0] += a1 * b0; acc[1][1] += a1 * b1; acc[1][2] += a1 * b2; acc[1][3] += a1 * b3;
            acc[2][0] += a2 * b0; acc[2][1] += a2 * b1; acc[2][2] += a2 * b2; acc[2][3] += a2 * b3;
            acc[3][0] += a3 * b0; acc[3][1] += a3 * b1; acc[3][2] += a3 * b2; acc[3][3] += a3 * b3;
        }
        __syncthreads();
    }
#pragma unroll
    for (int m = 0; m < 4; ++m) {
        int gr = r0 + ty * 4 + m;
        if (gr < Kn) {
#pragma unroll
            for (int n = 0; n < 4; ++n) {
                int gj = j0 + tx * 4 + n;
                if (gj < Kn) out[gr * Kn + gj] = acc[m][n];
            }
        }
    }
}

// ---------------------------------------------------------------------------
// K3: per (b,i): solve (AAt[b] + lambda*diag(D[b,i,:])) x = BAt[b,i,:].
// Whole 200x201 augmented matrix in LDS. Blocked no-pivot LU, NB=8:
//   phase P: wave 0 factors the 8-col panel entirely in registers
//            (4 row-chunks/lane — 256 rows >= 200; the R2 bug was 3 chunks
//            = 192 rows, which missed rows 192..199 at k=0) — no barriers.
//   phase U: 512 threads apply L8^{-1} to U-block rows (one column each,
//            28-FMA register recurrence).
//   phase T: rank-8 trailing update, final U cached in VGPRs, one row-set
//            per wave.
// 3 barriers per k-step (75 total vs 200 in R1). Back-substitution keeps
// y in wave-0 registers, broadcasts x via __shfl, zero LDS writes.
// ---------------------------------------------------------------------------
template<int QQ>
__device__ __forceinline__ void back_range(float y[4], const float* sM,
                                           const float* sInv, int lane,
                                           int khi, int klo)
{
    for (int k = khi; k >= klo; --k) {
        float xk = __shfl(y[QQ], k & 63) * sInv[k];
        if (lane == (k & 63)) y[QQ] = xk;
#pragma unroll
        for (int q2 = 0; q2 <= QQ; ++q2) {
            int r = lane + 64 * q2;
            if (r < k) y[q2] -= sM[r * 201 + k] * xk;
        }
    }
}

__global__ __launch_bounds__(512) void k_solve(
    const float* __restrict__ AAT,
    const float* __restrict__ evalx, const float* __restrict__ evaly,
    const float* __restrict__ graw, const float* __restrict__ lraw,
    float* __restrict__ out)
{
    __shared__ float sM[Kn * 201];
    __shared__ float sInv[Kn];
    __shared__ float sAux[8];
    const int bid = blockIdx.x;
    const int b = bid / 200;
    const int i = bid - b * 200;
    const int tid = threadIdx.x;
    const float* __restrict__ Sb = AAT + b * 40000;
    const float* __restrict__ Rb = AAT + 320000 + bid * 200;
    const float* __restrict__ ex = evalx + b * Kn;
    const float* __restrict__ ey = evaly + b * Kn;

    // load S (stride 201) and rhs (column 200)
    for (int e = tid; e < 40000; e += 512) {
        int r = e / 200;
        int c = e - r * 200;
        sM[r * 201 + c] = Sb[e];
    }
    if (tid < 200) sM[tid * 201 + 200] = Rb[tid];

    // scaling = max(max ex, max ey) over the batch (wave 0)
    if (tid < 64) {
        float mx = 0.f;
        for (int j = tid; j < 200; j += 64) mx = fmaxf(mx, fmaxf(ex[j], ey[j]));
#pragma unroll
        for (int s = 32; s > 0; s >>= 1) mx = fmaxf(mx, __shfl_down(mx, s));
        if (tid == 0) sAux[0] = mx;
    }
    __syncthreads();

    // diagonal: += lambda * D[b,i,r]
    if (tid < 200) {
        int r = tid;
        float s = sAux[0];
        float g = 1.f / (1.f + expf(-graw[0]));
        float lr = lraw[0];
        float sp = fmaxf(lr, 0.f) + log1pf(expf(-fabsf(lr)));   // stable softplus
        float lmb = 10.f + sp * (990.f / 1000.f);
        lmb = fminf(fmaxf(lmb, 10.f), 1000.f);
        float gx = powf(ex[i] / s, g);
        float gy = powf(ey[r] / s, g);
        float d1 = 1.f / (gx * gx + 1.f);
        float d2 = 1.f / (gy * gy + 1.f);
        float re = gy * d2 - gx * d1;
        float im = d2 - d1;
        sM[r * 201 + r] += lmb * (re * re + im * im);
    }
    __syncthreads();

    const int w = tid >> 6, l = tid & 63;

    // blocked LU, NB = 8, 25 steps
    for (int k = 0; k < 200; k += 8) {
        // ---- phase P: wave 0 factors the panel (rows k..199, cols k..k+7)
        if (tid < 64) {
            float p[4][8];
#pragma unroll
            for (int q = 0; q < 4; ++q) {
                int r = k + l + 64 * q;
                if (r < 200) {
#pragma unroll
                    for (int c = 0; c < 8; ++c) p[q][c] = sM[r * 201 + k + c];
                } else {
#pragma unroll
                    for (int c = 0; c < 8; ++c) p[q][c] = 0.f;
                }
            }
#pragma unroll
            for (int c = 0; c < 8; ++c) {
                float pivc = __shfl(p[0][c], c);
                float invp = 1.0f / pivc;
                float pr[8];
#pragma unroll
                for (int j = c + 1; j < 8; ++j) pr[j] = __shfl(p[0][j], c);
#pragma unroll
                for (int q = 0; q < 4; ++q) {
                    int r = k + l + 64 * q;
                    bool act = (r < 200) && (q > 0 || l > c);
                    if (act) {
                        float f = p[q][c] * invp;
                        p[q][c] = f;
#pragma unroll
                        for (int j = c + 1; j < 8; ++j) p[q][j] -= f * pr[j];
                    }
                }
            }
#pragma unroll
            for (int q = 0; q < 4; ++q) {
                int r = k + l + 64 * q;
                if (r < 200) {
#pragma unroll
                    for (int c = 0; c < 8; ++c) sM[r * 201 + k + c] = p[q][c];
                }
            }
        }
        __syncthreads();

        // ---- phase U: rows k..k+7, cols k+8..200 get L8^{-1} applied.
        // One column per thread (<=193 active).
        {
            int j = k + 8 + tid;
            if (j <= 200) {
                float u[8];
#pragma unroll
                for (int c = 0; c < 8; ++c) u[c] = sM[(k + c) * 201 + j];
#pragma unroll
                for (int c = 1; c < 8; ++c) {
                    float a = u[c];
#pragma unroll
                    for (int c2 = 0; c2 < c; ++c2)
                        a -= sM[(k + c) * 201 + k + c2] * u[c2];
                    u[c] = a;
                }
#pragma unroll
                for (int c = 0; c < 8; ++c) sM[(k + c) * 201 + j] = u[c];
            }
        }
        __syncthreads();

        // ---- phase T: rank-8 trailing update, rows k+8..199, cols k+8..200
        {
            const int jb0 = k + 8;
            float pv[4][8];
#pragma unroll
            for (int ch = 0; ch < 4; ++ch) {
                int j = jb0 + ch * 64 + l;
                if (j <= 200) {
#pragma unroll
                    for (int c = 0; c < 8; ++c) pv[ch][c] = sM[(k + c) * 201 + j];
                }
            }
            for (int r = k + 8 + w; r < 200; r += 8) {
                float f[8];
#pragma unroll
                for (int c = 0; c < 8; ++c) f[c] = sM[r * 201 + k + c];
#pragma unroll
                for (int ch = 0; ch < 4; ++ch) {
                    int j = jb0 + ch * 64 + l;
                    if (j <= 200) {
                        float a = sM[r * 201 + j];
#pragma unroll
                        for (int c = 0; c < 8; ++c) a -= f[c] * pv[ch][c];
                        sM[r * 201 + j] = a;
                    }
                }
            }
        }
        __syncthreads();
    }

    // reciprocal diagonal (parallel), then back-substitution on wave 0
    if (tid < 200) sInv[tid] = 1.0f / sM[tid * 201 + tid];
    __syncthreads();

    if (tid < 64) {
        float y[4];
#pragma unroll
        for (int q = 0; q < 4; ++q) {
            int r = tid + 64 * q;
            y[q] = (r < 200) ? sM[r * 201 + 200] : 0.f;
        }
        back_range<3>(y, sM, sInv, tid, 199, 192);
        back_range<2>(y, sM, sInv, tid, 191, 128);
        back_range<1>(y, sM, sInv, tid, 127, 64);
        back_range<0>(y, sM, sInv, tid, 63, 0);
#pragma unroll
        for (int q = 0; q < 4; ++q) {
            int r = tid + 64 * q;
            if (r < 200) out[bid * 200 + r] = y[q];
        }
    }
}

// ---------------------------------------------------------------------------
extern "C" void kernel_launch(void* const* d_in, const int* in_sizes, int n_in,
                              void* d_out, int out_size, void* d_ws, size_t ws_size,
                              hipStream_t stream)
{
    const float* fx   = (const float*)d_in[0];   // feat_x   [8,5000,256]
    const float* fy   = (const float*)d_in[1];   // feat_y
    const float* evx  = (const float*)d_in[2];   // evals_x  [8,200]
    const float* evy  = (const float*)d_in[3];   // evals_y
    const float* etx  = (const float*)d_in[4];   // evecs_trans_x [8,200,5000]
    const float* ety  = (const float*)d_in[5];   // evecs_trans_y
    const float* graw = (const float*)d_in[6];   // gamma_raw scalar
    const float* lraw = (const float*)d_in[7];   // lambda_raw scalar
    float* out = (float*)d_out;
    float* ws  = (float*)d_ws;

    // zero the split-K accumulation region (AB)
    hipMemsetAsync(ws + AB_OFF, 0, (size_t)16 * Kn * Cn * sizeof(float), stream);

    k_gemm_ab<<<dim3(2048), dim3(256), 0, stream>>>(fx, fy, etx, ety, ws + AB_OFF);
    k_gemm_nt<<<dim3(256), dim3(256), 0, stream>>>(ws + AB_OFF, ws + AAT_OFF);
    k_solve<<<dim3(1600), dim3(512), 0, stream>>>(ws + AAT_OFF, evx, evy, graw, lraw, out);
}